// Round 6
// baseline (462.691 us; speedup 1.0000x reference)
//
#include <hip/hip_runtime.h>
#include <hip/hip_bf16.h>
#include <cstdint>
#include <math.h>

#define SEQ    2048
#define DMODEL 1024
#define NHEAD  16
#define DHEAD  64
#define NBLK   768   // 3 blocks/CU on 256 CUs — co-resident by resource math
                     // (validated r5: barrier completed, no deadlock)

typedef __bf16 bf16;
typedef __bf16 bf16x8 __attribute__((ext_vector_type(8)));
typedef float  f32x4  __attribute__((ext_vector_type(4)));

typedef __attribute__((address_space(3))) uint32_t lds_u32;
typedef __attribute__((address_space(1))) const uint32_t global_u32;

__device__ __forceinline__ void async_load16(const void* g, void* l) {
    __builtin_amdgcn_global_load_lds((global_u32*)g, (lds_u32*)l, 16, 0, 0);
}

struct Params {
    const float *query, *key, *value;
    const float *wq, *bq, *wk, *bk, *wv, *bv, *wo, *bo;
    float* out;
    bf16 *qx, *kx, *vx;
    bf16 *wqT, *wkT, *wvT, *woT;
    bf16 *qp, *kp, *vp, *ao;
    int* bar;   // zeroed by hipMemsetAsync before launch
};

// Software grid barrier: monotone counter, phase target = phase * NBLK.
// A block can only add for phase p+1 after count >= p*NBLK, so one counter
// is race-free. Agent-scope release/acquire handles cross-XCD visibility.
__device__ __forceinline__ void grid_barrier(int* cnt, int target) {
    __syncthreads();
    if (threadIdx.x == 0) {
        __hip_atomic_fetch_add(cnt, 1, __ATOMIC_RELEASE, __HIP_MEMORY_SCOPE_AGENT);
        while (__hip_atomic_load(cnt, __ATOMIC_ACQUIRE, __HIP_MEMORY_SCOPE_AGENT) < target)
            __builtin_amdgcn_s_sleep(2);
    }
    __syncthreads();
}

// ---------------------------------------------------------------------------
// 64(M) x 128(N) GEMM tile, K=1024, BK=32, bf16 MFMA 16x16x32, m97 staging.
template <typename OutT>
__device__ __forceinline__ void gemm_tile(
    const bf16* __restrict__ A, const bf16* __restrict__ BT,
    const float* __restrict__ bias, OutT* __restrict__ C,
    int m0, int n0, char* smem) {
    const int tid = threadIdx.x;
    const int w = tid >> 6, lane = tid & 63;
    const int wm = w >> 1, wn = w & 1;
    const int lr = lane & 15, quad = lane >> 4;
    bf16* sA = (bf16*)smem;            // [64][32]
    bf16* sB = (bf16*)(smem + 4096);   // [128][32]

    f32x4 acc[2][4] = {};
    float bia[4];
#pragma unroll
    for (int ni = 0; ni < 4; ++ni) bia[ni] = bias[n0 + wn * 64 + ni * 16 + lr];

    for (int kt = 0; kt < 1024; kt += 32) {
        // 768 16B chunks: A rows 64 (256 chunks), B rows 128 (512 chunks)
#pragma unroll
        for (int r = 0; r < 3; ++r) {
            const int cbase = (w * 3 + r) * 64;   // wave-uniform
            if (cbase < 256) {
                const int c = cbase + lane;
                const int row = c >> 2, ch = c & 3;
                async_load16(A + (size_t)(m0 + row) * 1024 + kt + ch * 8,
                             smem + cbase * 16);
            } else {
                const int cb = cbase - 256 + lane;
                const int row = cb >> 2, ch = cb & 3;
                async_load16(BT + (size_t)(n0 + row) * 1024 + kt + ch * 8,
                             smem + 4096 + (cbase - 256) * 16);
            }
        }
        __syncthreads();

        bf16x8 af[2], bfr[4];
#pragma unroll
        for (int mi = 0; mi < 2; ++mi)
            af[mi] = *(const bf16x8*)&sA[(wm * 32 + mi * 16 + lr) * 32 + quad * 8];
#pragma unroll
        for (int ni = 0; ni < 4; ++ni)
            bfr[ni] = *(const bf16x8*)&sB[(wn * 64 + ni * 16 + lr) * 32 + quad * 8];
#pragma unroll
        for (int mi = 0; mi < 2; ++mi)
#pragma unroll
            for (int ni = 0; ni < 4; ++ni)
                acc[mi][ni] = __builtin_amdgcn_mfma_f32_16x16x32_bf16(
                    af[mi], bfr[ni], acc[mi][ni], 0, 0, 0);
        __syncthreads();
    }

    // C/D layout: col=lane&15, row=quad*4+reg
#pragma unroll
    for (int mi = 0; mi < 2; ++mi)
#pragma unroll
        for (int ni = 0; ni < 4; ++ni) {
            const int row = m0 + wm * 32 + mi * 16 + quad * 4;
            const int col = n0 + wn * 64 + ni * 16 + lr;
            const f32x4 vv = acc[mi][ni];
#pragma unroll
            for (int r = 0; r < 4; ++r)
                C[(size_t)(row + r) * 1024 + col] = (OutT)(vv[r] + bia[ni]);
        }
}

// ---------------------------------------------------------------------------
// Persistent fused kernel: prep -> proj(q,k,v) -> attn -> out-proj, with
// software grid barriers between stages. Regular launch, 768 blocks.
__global__ __launch_bounds__(256, 3) void fused_kernel(Params p) {
    __shared__ __align__(16) char smem[12288];
    const int bid = blockIdx.x;
    const int tid = threadIdx.x;
    const int lane = tid & 63, wv = tid >> 6;

    // ======== stage 1: prep — casts (3072 units) + W transposes (4096 units)
    {
        float (*tile)[33] = (float(*)[33])smem;
        for (int i = 0; i < 10; ++i) {
            const int u = bid + NBLK * i;
            if (u >= 7168) break;
            if (u < 3072) {
                const int z = u >> 10;
                const float* src = (z == 0) ? p.query : (z == 1) ? p.key : p.value;
                bf16* dst        = (z == 0) ? p.qx : (z == 1) ? p.kx : p.vx;
                const int idx = (u & 1023) * 256 + tid;
                const float4* s4 = (const float4*)src;
                float4 a = s4[idx * 2 + 0];
                float4 b = s4[idx * 2 + 1];
                bf16x8 o;
                o[0] = (bf16)a.x; o[1] = (bf16)a.y; o[2] = (bf16)a.z; o[3] = (bf16)a.w;
                o[4] = (bf16)b.x; o[5] = (bf16)b.y; o[6] = (bf16)b.z; o[7] = (bf16)b.w;
                ((bf16x8*)dst)[idx] = o;
            } else {
                const int b2 = u - 3072;
                const int z = b2 >> 10, rem = b2 & 1023;
                const float* wsrc = (z == 0) ? p.wq : (z == 1) ? p.wk : (z == 2) ? p.wv : p.wo;
                bf16* t = (z == 0) ? p.wqT : (z == 1) ? p.wkT : (z == 2) ? p.wvT : p.woT;
                const int tx = tid & 31, ty = tid >> 5;
                const int kbase = (rem >> 5) * 32, nbase = (rem & 31) * 32;
                __syncthreads();  // protect tile reuse across i-iterations
#pragma unroll
                for (int ii = 0; ii < 4; ++ii)
                    tile[ty + 8 * ii][tx] =
                        wsrc[(size_t)(kbase + ty + 8 * ii) * 1024 + nbase + tx];
                __syncthreads();
#pragma unroll
                for (int ii = 0; ii < 4; ++ii)
                    t[(size_t)(nbase + 8 * ii + ty) * 1024 + kbase + tx] =
                        (bf16)tile[tx][ty + 8 * ii];
            }
        }
    }
    grid_barrier(p.bar, NBLK);

    // ======== stage 2: q/k/v projections — 768 tiles (64x128), one per block
    {
        const int z = bid >> 8, t8 = bid & 255;
        const int m0 = (t8 >> 3) * 64, n0 = (t8 & 7) * 128;
        const bf16* A  = (z == 0) ? p.qx : (z == 1) ? p.kx : p.vx;
        const bf16* BT = (z == 0) ? p.wqT : (z == 1) ? p.wkT : p.wvT;
        const float* bb = (z == 0) ? p.bq : (z == 1) ? p.bk : p.bv;
        bf16* C        = (z == 0) ? p.qp : (z == 1) ? p.kp : p.vp;
        gemm_tile<bf16>(A, BT, bb, C, m0, n0, smem);
    }
    grid_barrier(p.bar, 2 * NBLK);

    // ======== stage 3: sparse attention (analytic layout)
    // NHEAD*SEQ = 32768 wave-jobs = 8192 block-jobs over 768 blocks: 11 rounds
    for (int j = 0; j < 11; ++j) {
        const int job = bid + NBLK * j;
        if (job >= NHEAD * SEQ / 4) break;
        const int pp = job * 4 + wv;
        const int s = __builtin_amdgcn_readfirstlane(pp & (SEQ - 1));
        const int h = __builtin_amdgcn_readfirstlane(pp >> 11);
        const int hoff = h * DHEAD + lane;

        const int sT = s >> 8, sH = (s >> 4) & 15;
        const int sLow = s & 255, sTop = s & ~255, sW = s & 15;
        const int L = ((s < 3) ? s : 3) + 1;
        const int cnt = L + sT + sH;  // <= 26
        auto nz_t = [&](int c) -> int {
            return (c < L) ? (s - c)
                 : (c < L + sT) ? (((c - L) << 8) + sLow)
                 : (c < cnt) ? (sTop + ((c - L - sT) << 4) + sW)
                 : s;  // padded (masked below)
        };

        const float q = (float)p.qp[(size_t)s * DMODEL + hoff];
        float pr[32];
#pragma unroll
        for (int c = 0; c < 32; ++c)
            pr[c] = q * (float)p.kp[(size_t)nz_t(c) * DMODEL + hoff];
        // 5-step tree transpose-reduce: lane l ends with dot for c = l&31
#pragma unroll
        for (int step = 0; step < 5; ++step) {
            const int mask = 1 << step;
            const int half = 32 >> (step + 1);
            const bool hi = (lane & mask) != 0;
#pragma unroll
            for (int c = 0; c < half; ++c) {
                const float a = pr[2 * c], b = pr[2 * c + 1];
                const float mine = hi ? b : a;
                const float oth  = hi ? a : b;
                pr[c] = mine + __shfl_xor(oth, mask);
            }
        }
        const float dotv = pr[0] + __shfl_xor(pr[0], 32);

        const int c_lane = lane & 31;
        const float logit = (c_lane < cnt) ? dotv * 0.125f : -1e30f;
        float m = logit;
        m = fmaxf(m, __shfl_xor(m, 1)); m = fmaxf(m, __shfl_xor(m, 2));
        m = fmaxf(m, __shfl_xor(m, 4)); m = fmaxf(m, __shfl_xor(m, 8));
        m = fmaxf(m, __shfl_xor(m, 16));
        const float e = __expf(logit - m);
        float ssum = e;
        ssum += __shfl_xor(ssum, 1); ssum += __shfl_xor(ssum, 2);
        ssum += __shfl_xor(ssum, 4); ssum += __shfl_xor(ssum, 8);
        ssum += __shfl_xor(ssum, 16);
        const float prob = e / ssum;

        float acc = 0.f;
#pragma unroll
        for (int c = 0; c < 32; ++c)
            acc += __shfl(prob, c) * (float)p.vp[(size_t)nz_t(c) * DMODEL + hoff];
        p.ao[(size_t)s * DMODEL + hoff] = (bf16)acc;
    }
    grid_barrier(p.bar, 3 * NBLK);

    // ======== stage 4: output projection — 256 tiles (64x128) on blocks 0-255
    if (bid < 256) {
        const int m0 = (bid >> 3) * 64, n0 = (bid & 7) * 128;
        gemm_tile<float>(p.ao, p.woT, p.bo, p.out, m0, n0, smem);
    }
}

// ---------------------------------------------------------------------------
extern "C" void kernel_launch(void* const* d_in, const int* in_sizes, int n_in,
                              void* d_out, int out_size, void* d_ws, size_t ws_size,
                              hipStream_t stream) {
    char* ws = (char*)d_ws;
    auto alloc = [&](size_t bytes) {
        char* pp = ws;
        ws += (bytes + 255) & ~(size_t)255;
        return pp;
    };

    Params prm;
    prm.query = (const float*)d_in[0];
    prm.key   = (const float*)d_in[1];
    prm.value = (const float*)d_in[2];
    prm.wq = (const float*)d_in[3];  prm.bq = (const float*)d_in[4];
    prm.wk = (const float*)d_in[5];  prm.bk = (const float*)d_in[6];
    prm.wv = (const float*)d_in[7];  prm.bv = (const float*)d_in[8];
    prm.wo = (const float*)d_in[9];  prm.bo = (const float*)d_in[10];
    prm.out = (float*)d_out;
    prm.qx  = (bf16*)alloc((size_t)SEQ * DMODEL * 2);
    prm.kx  = (bf16*)alloc((size_t)SEQ * DMODEL * 2);
    prm.vx  = (bf16*)alloc((size_t)SEQ * DMODEL * 2);
    prm.wqT = (bf16*)alloc((size_t)DMODEL * DMODEL * 2);
    prm.wkT = (bf16*)alloc((size_t)DMODEL * DMODEL * 2);
    prm.wvT = (bf16*)alloc((size_t)DMODEL * DMODEL * 2);
    prm.woT = (bf16*)alloc((size_t)DMODEL * DMODEL * 2);
    prm.qp  = (bf16*)alloc((size_t)SEQ * DMODEL * 2);
    prm.kp  = (bf16*)alloc((size_t)SEQ * DMODEL * 2);
    prm.vp  = (bf16*)alloc((size_t)SEQ * DMODEL * 2);
    prm.ao  = (bf16*)alloc((size_t)SEQ * DMODEL * 2);
    prm.bar = (int*)alloc(256);

    // zero the barrier counter (ws is re-poisoned 0xAA before every call)
    hipMemsetAsync(prm.bar, 0, 256, stream);
    fused_kernel<<<dim3(NBLK), dim3(256), 0, stream>>>(prm);
}

// Round 7
// 347.576 us; speedup vs baseline: 1.3312x; 1.3312x over previous
//
#include <hip/hip_runtime.h>
#include <hip/hip_bf16.h>
#include <cstdint>
#include <math.h>

#define SEQ    2048
#define DMODEL 1024
#define NHEAD  16
#define DHEAD  64
#define NBLK   768   // 3 blocks/CU on 256 CUs — co-resident (validated r5/r6)
#define NGRP   48    // barrier groups: 16 blocks/group, counters on separate lines
#define GRPSZ  (NBLK / NGRP)

typedef __bf16 bf16;
typedef __bf16 bf16x8 __attribute__((ext_vector_type(8)));
typedef float  f32x4  __attribute__((ext_vector_type(4)));

typedef __attribute__((address_space(3))) uint32_t lds_u32;
typedef __attribute__((address_space(1))) const uint32_t global_u32;

__device__ __forceinline__ void async_load16(const void* g, void* l) {
    __builtin_amdgcn_global_load_lds((global_u32*)g, (lds_u32*)l, 16, 0, 0);
}

struct Params {
    const float *query, *key, *value;
    const float *wq, *bq, *wk, *bk, *wv, *bv, *wo, *bo;
    float* out;
    bf16 *qx, *kx, *vx;
    bf16 *wqT, *wkT, *wvT, *woT;
    bf16 *qp, *kp, *vp, *ao;
    int* bar;   // [NGRP*64] arrive counters (256B-spaced) + [64] root; memset 0
};

// Two-level grid barrier (r6 post-mortem: single-line version cost ~80us/barrier
// from 768 serialized agent-scope RMWs + 767 pollers on one LLC line).
// Level 1: block adds acq_rel to its group's line (16 adds/line, 48 lines in
// parallel). Level 2: group's last arriver adds to root (48 adds). Spin only
// on the read-only root line, 0.43us poll period. Acquire(root) syncs-with
// leader's release, which acquired its group -> transitive with all members.
__device__ __forceinline__ void grid_barrier(int* bar, int phase, bool wait) {
    __syncthreads();
    if (threadIdx.x == 0) {
        int* arr  = bar + (blockIdx.x % NGRP) * 64;
        int* root = bar + NGRP * 64;
        const int old = __hip_atomic_fetch_add(arr, 1, __ATOMIC_ACQ_REL,
                                               __HIP_MEMORY_SCOPE_AGENT);
        if (old == phase * GRPSZ + (GRPSZ - 1))
            __hip_atomic_fetch_add(root, 1, __ATOMIC_ACQ_REL,
                                   __HIP_MEMORY_SCOPE_AGENT);
        if (wait) {
            while (__hip_atomic_load(root, __ATOMIC_ACQUIRE,
                                     __HIP_MEMORY_SCOPE_AGENT) < (phase + 1) * NGRP)
                __builtin_amdgcn_s_sleep(16);
        }
    }
    __syncthreads();
}

// ---------------------------------------------------------------------------
// 64(M) x 128(N) GEMM tile, K=1024, BK=32, bf16 MFMA 16x16x32, m97 staging.
template <typename OutT>
__device__ __forceinline__ void gemm_tile(
    const bf16* __restrict__ A, const bf16* __restrict__ BT,
    const float* __restrict__ bias, OutT* __restrict__ C,
    int m0, int n0, char* smem) {
    const int tid = threadIdx.x;
    const int w = tid >> 6, lane = tid & 63;
    const int wm = w >> 1, wn = w & 1;
    const int lr = lane & 15, quad = lane >> 4;
    bf16* sA = (bf16*)smem;            // [64][32]
    bf16* sB = (bf16*)(smem + 4096);   // [128][32]

    f32x4 acc[2][4] = {};
    float bia[4];
#pragma unroll
    for (int ni = 0; ni < 4; ++ni) bia[ni] = bias[n0 + wn * 64 + ni * 16 + lr];

    for (int kt = 0; kt < 1024; kt += 32) {
        // 768 16B chunks: A rows 64 (256 chunks), B rows 128 (512 chunks)
#pragma unroll
        for (int r = 0; r < 3; ++r) {
            const int cbase = (w * 3 + r) * 64;   // wave-uniform
            if (cbase < 256) {
                const int c = cbase + lane;
                const int row = c >> 2, ch = c & 3;
                async_load16(A + (size_t)(m0 + row) * 1024 + kt + ch * 8,
                             smem + cbase * 16);
            } else {
                const int cb = cbase - 256 + lane;
                const int row = cb >> 2, ch = cb & 3;
                async_load16(BT + (size_t)(n0 + row) * 1024 + kt + ch * 8,
                             smem + 4096 + (cbase - 256) * 16);
            }
        }
        __syncthreads();

        bf16x8 af[2], bfr[4];
#pragma unroll
        for (int mi = 0; mi < 2; ++mi)
            af[mi] = *(const bf16x8*)&sA[(wm * 32 + mi * 16 + lr) * 32 + quad * 8];
#pragma unroll
        for (int ni = 0; ni < 4; ++ni)
            bfr[ni] = *(const bf16x8*)&sB[(wn * 64 + ni * 16 + lr) * 32 + quad * 8];
#pragma unroll
        for (int mi = 0; mi < 2; ++mi)
#pragma unroll
            for (int ni = 0; ni < 4; ++ni)
                acc[mi][ni] = __builtin_amdgcn_mfma_f32_16x16x32_bf16(
                    af[mi], bfr[ni], acc[mi][ni], 0, 0, 0);
        __syncthreads();
    }

    // C/D layout: col=lane&15, row=quad*4+reg
#pragma unroll
    for (int mi = 0; mi < 2; ++mi)
#pragma unroll
        for (int ni = 0; ni < 4; ++ni) {
            const int row = m0 + wm * 32 + mi * 16 + quad * 4;
            const int col = n0 + wn * 64 + ni * 16 + lr;
            const f32x4 vv = acc[mi][ni];
#pragma unroll
            for (int r = 0; r < 4; ++r)
                C[(size_t)(row + r) * 1024 + col] = (OutT)(vv[r] + bia[ni]);
        }
}

// ---------------------------------------------------------------------------
// Persistent fused kernel: prep -> proj(q,k,v) -> attn -> out-proj, with
// two-level software grid barriers between stages.
__global__ __launch_bounds__(256, 3) void fused_kernel(Params p) {
    __shared__ __align__(16) char smem[12288];
    const int bid = blockIdx.x;
    const int tid = threadIdx.x;
    const int lane = tid & 63, wv = tid >> 6;

    // ======== stage 1: prep — casts (3072 units) + W transposes (4096 units)
    {
        float (*tile)[33] = (float(*)[33])smem;
        for (int i = 0; i < 10; ++i) {
            const int u = bid + NBLK * i;
            if (u >= 7168) break;
            if (u < 3072) {
                const int z = u >> 10;
                const float* src = (z == 0) ? p.query : (z == 1) ? p.key : p.value;
                bf16* dst        = (z == 0) ? p.qx : (z == 1) ? p.kx : p.vx;
                const int idx = (u & 1023) * 256 + tid;
                const float4* s4 = (const float4*)src;
                float4 a = s4[idx * 2 + 0];
                float4 b = s4[idx * 2 + 1];
                bf16x8 o;
                o[0] = (bf16)a.x; o[1] = (bf16)a.y; o[2] = (bf16)a.z; o[3] = (bf16)a.w;
                o[4] = (bf16)b.x; o[5] = (bf16)b.y; o[6] = (bf16)b.z; o[7] = (bf16)b.w;
                ((bf16x8*)dst)[idx] = o;
            } else {
                const int b2 = u - 3072;
                const int z = b2 >> 10, rem = b2 & 1023;
                const float* wsrc = (z == 0) ? p.wq : (z == 1) ? p.wk : (z == 2) ? p.wv : p.wo;
                bf16* t = (z == 0) ? p.wqT : (z == 1) ? p.wkT : (z == 2) ? p.wvT : p.woT;
                const int tx = tid & 31, ty = tid >> 5;
                const int kbase = (rem >> 5) * 32, nbase = (rem & 31) * 32;
                __syncthreads();  // protect tile reuse across i-iterations
#pragma unroll
                for (int ii = 0; ii < 4; ++ii)
                    tile[ty + 8 * ii][tx] =
                        wsrc[(size_t)(kbase + ty + 8 * ii) * 1024 + nbase + tx];
                __syncthreads();
#pragma unroll
                for (int ii = 0; ii < 4; ++ii)
                    t[(size_t)(nbase + 8 * ii + ty) * 1024 + kbase + tx] =
                        (bf16)tile[tx][ty + 8 * ii];
            }
        }
    }
    grid_barrier(p.bar, 0, true);

    // ======== stage 2: q/k/v projections — 768 tiles (64x128), one per block
    {
        const int z = bid >> 8, t8 = bid & 255;
        const int m0 = (t8 >> 3) * 64, n0 = (t8 & 7) * 128;
        const bf16* A  = (z == 0) ? p.qx : (z == 1) ? p.kx : p.vx;
        const bf16* BT = (z == 0) ? p.wqT : (z == 1) ? p.wkT : p.wvT;
        const float* bb = (z == 0) ? p.bq : (z == 1) ? p.bk : p.bv;
        bf16* C        = (z == 0) ? p.qp : (z == 1) ? p.kp : p.vp;
        gemm_tile<bf16>(A, BT, bb, C, m0, n0, smem);
    }
    grid_barrier(p.bar, 1, true);

    // ======== stage 3: sparse attention (analytic layout)
    // NHEAD*SEQ = 32768 wave-jobs = 8192 block-jobs over 768 blocks: 11 rounds
    for (int j = 0; j < 11; ++j) {
        const int job = bid + NBLK * j;
        if (job >= NHEAD * SEQ / 4) break;
        const int pp = job * 4 + wv;
        const int s = __builtin_amdgcn_readfirstlane(pp & (SEQ - 1));
        const int h = __builtin_amdgcn_readfirstlane(pp >> 11);
        const int hoff = h * DHEAD + lane;

        const int sT = s >> 8, sH = (s >> 4) & 15;
        const int sLow = s & 255, sTop = s & ~255, sW = s & 15;
        const int L = ((s < 3) ? s : 3) + 1;
        const int cnt = L + sT + sH;  // <= 26
        auto nz_t = [&](int c) -> int {
            return (c < L) ? (s - c)
                 : (c < L + sT) ? (((c - L) << 8) + sLow)
                 : (c < cnt) ? (sTop + ((c - L - sT) << 4) + sW)
                 : s;  // padded (masked below)
        };

        const float q = (float)p.qp[(size_t)s * DMODEL + hoff];
        float pr[32];
#pragma unroll
        for (int c = 0; c < 32; ++c)
            pr[c] = q * (float)p.kp[(size_t)nz_t(c) * DMODEL + hoff];
        // 5-step tree transpose-reduce: lane l ends with dot for c = l&31
#pragma unroll
        for (int step = 0; step < 5; ++step) {
            const int mask = 1 << step;
            const int half = 32 >> (step + 1);
            const bool hi = (lane & mask) != 0;
#pragma unroll
            for (int c = 0; c < half; ++c) {
                const float a = pr[2 * c], b = pr[2 * c + 1];
                const float mine = hi ? b : a;
                const float oth  = hi ? a : b;
                pr[c] = mine + __shfl_xor(oth, mask);
            }
        }
        const float dotv = pr[0] + __shfl_xor(pr[0], 32);

        const int c_lane = lane & 31;
        const float logit = (c_lane < cnt) ? dotv * 0.125f : -1e30f;
        float m = logit;
        m = fmaxf(m, __shfl_xor(m, 1)); m = fmaxf(m, __shfl_xor(m, 2));
        m = fmaxf(m, __shfl_xor(m, 4)); m = fmaxf(m, __shfl_xor(m, 8));
        m = fmaxf(m, __shfl_xor(m, 16));
        const float e = __expf(logit - m);
        float ssum = e;
        ssum += __shfl_xor(ssum, 1); ssum += __shfl_xor(ssum, 2);
        ssum += __shfl_xor(ssum, 4); ssum += __shfl_xor(ssum, 8);
        ssum += __shfl_xor(ssum, 16);
        const float prob = e / ssum;

        float acc = 0.f;
#pragma unroll
        for (int c = 0; c < 32; ++c)
            acc += __shfl(prob, c) * (float)p.vp[(size_t)nz_t(c) * DMODEL + hoff];
        p.ao[(size_t)s * DMODEL + hoff] = (bf16)acc;
    }
    // blocks >=256 only arrive (no poll) — they exit after this
    grid_barrier(p.bar, 2, bid < 256);

    // ======== stage 4: output projection — 256 tiles (64x128) on blocks 0-255
    if (bid < 256) {
        const int m0 = (bid >> 3) * 64, n0 = (bid & 7) * 128;
        gemm_tile<float>(p.ao, p.woT, p.bo, p.out, m0, n0, smem);
    }
}

// ---------------------------------------------------------------------------
extern "C" void kernel_launch(void* const* d_in, const int* in_sizes, int n_in,
                              void* d_out, int out_size, void* d_ws, size_t ws_size,
                              hipStream_t stream) {
    char* ws = (char*)d_ws;
    auto alloc = [&](size_t bytes) {
        char* pp = ws;
        ws += (bytes + 255) & ~(size_t)255;
        return pp;
    };

    Params prm;
    prm.query = (const float*)d_in[0];
    prm.key   = (const float*)d_in[1];
    prm.value = (const float*)d_in[2];
    prm.wq = (const float*)d_in[3];  prm.bq = (const float*)d_in[4];
    prm.wk = (const float*)d_in[5];  prm.bk = (const float*)d_in[6];
    prm.wv = (const float*)d_in[7];  prm.bv = (const float*)d_in[8];
    prm.wo = (const float*)d_in[9];  prm.bo = (const float*)d_in[10];
    prm.out = (float*)d_out;
    prm.qx  = (bf16*)alloc((size_t)SEQ * DMODEL * 2);
    prm.kx  = (bf16*)alloc((size_t)SEQ * DMODEL * 2);
    prm.vx  = (bf16*)alloc((size_t)SEQ * DMODEL * 2);
    prm.wqT = (bf16*)alloc((size_t)DMODEL * DMODEL * 2);
    prm.wkT = (bf16*)alloc((size_t)DMODEL * DMODEL * 2);
    prm.wvT = (bf16*)alloc((size_t)DMODEL * DMODEL * 2);
    prm.woT = (bf16*)alloc((size_t)DMODEL * DMODEL * 2);
    prm.qp  = (bf16*)alloc((size_t)SEQ * DMODEL * 2);
    prm.kp  = (bf16*)alloc((size_t)SEQ * DMODEL * 2);
    prm.vp  = (bf16*)alloc((size_t)SEQ * DMODEL * 2);
    prm.ao  = (bf16*)alloc((size_t)SEQ * DMODEL * 2);
    prm.bar = (int*)alloc((NGRP * 64 + 64) * sizeof(int));

    // zero all barrier counters (ws is re-poisoned 0xAA before every call)
    hipMemsetAsync(prm.bar, 0, (NGRP * 64 + 64) * sizeof(int), stream);
    fused_kernel<<<dim3(NBLK), dim3(256), 0, stream>>>(prm);
}